// Round 3
// baseline (159.970 us; speedup 1.0000x reference)
//
#include <hip/hip_runtime.h>

// Problem constants (from reference)
#define N_NODES 12500
#define N_EDGES 200000
#define DIM 32          // IN == OUT == ATTN == 32
#define N_REL 200
#define N_BASES 50

#define OUT_ELEMS   (N_NODES * DIM)
#define ZERO_BLOCKS ((OUT_ELEMS + 1023) / 1024)   // 391

// Padded edge capacity: per-rel lists padded to multiples of 16.
// 200000 + 200*15 = 203000, round up to multiple of 64 for the edge grid.
// Note: dummy slots are EXACTLY PE_MAX - N_EDGES = 3008 (per-rel pads + tail),
// so scatter's 8 extra blocks write them; no bulk init pass needed.
#define PE_MAX 203008
#define N_DUMMY_BLOCKS 8

// Counting-sort blocking: NB_BLK blocks each own a contiguous CHUNK of edges.
// Per-block LDS histograms + transposed [r][blk] count/base tables; the scan
// is one block with int4 reads + Hillis-Steele (R2 scan was a serial
// 200-iteration thread-0 loop + strided loads on the critical path).
#define NB_BLK 200
#define CHUNK 1000            // NB_BLK * CHUNK == N_EDGES exactly

// ws layout (bytes):
//   [0, 409600)         bf16 relwT_bf[200][32][32]  TRANSPOSED: [r][o][i]
//   [409600, +8192)     bf16 aw_bf[32][128]         (= A_w, row-major)
//   [417792, +2048)     bf16 slwT_bf[32][32]        (= slw transposed [j][i])
//   [419840, +160000)   int  blockCountsT[N_REL][NB_BLK]
//   [579840, +160000)   int  blockBaseT[N_REL][NB_BLK]
//   [739840, +816)      int  offs[201]   (offs[200] = padded total)
//   [740656, +800)      int  tots[200]
//   [741456, +16*PE_MAX) int4 slot4[PE_MAX]  {src, tgt(-1=dummy), eid, rel}
#define AWBF_OFF  (N_REL * 1024 * 2)
#define SLWT_OFF  (AWBF_OFF + 32 * 128 * 2)
#define BCT_OFF   (SLWT_OFF + 32 * 32 * 2)
#define BBT_OFF   (BCT_OFF + N_REL * NB_BLK * 4)
#define OFFS_OFF  (BBT_OFF + N_REL * NB_BLK * 4)
#define TOTS_OFF  (OFFS_OFF + 816)
#define SLOT_OFF  (TOTS_OFF + 800)               // 741456, 16B-aligned

typedef __attribute__((ext_vector_type(8))) short short8;   // 8 bf16 (4 VGPRs)
typedef __attribute__((ext_vector_type(4))) float f32x4;    // MFMA acc

__device__ __forceinline__ unsigned short f2bf(float x) {
    union { float f; unsigned u; } v; v.f = x;
    unsigned r = (v.u + 0x7FFFu + ((v.u >> 16) & 1u)) >> 16;
    return (unsigned short)r;
}

__device__ __forceinline__ short8 cvt8(float4 a, float4 b) {
    short8 r;
    r[0] = (short)f2bf(a.x); r[1] = (short)f2bf(a.y);
    r[2] = (short)f2bf(a.z); r[3] = (short)f2bf(a.w);
    r[4] = (short)f2bf(b.x); r[5] = (short)f2bf(b.y);
    r[6] = (short)f2bf(b.z); r[7] = (short)f2bf(b.w);
    return r;
}

#define MFMA(A, B, C) __builtin_amdgcn_mfma_f32_16x16x32_bf16(A, B, C, 0, 0, 0)

// Prep: [0,200) rel_w basis combine; [200,591) zero out; 591 converts Aw/slwT;
//   [592,792) per-block LDS histogram -> blockCountsT (transposed, no global
//   atomics). The R2 slot4-init pass is gone: scatter writes the 3008 dummies.
__global__ __launch_bounds__(256) void prep_kernel(
    const float* __restrict__ weight,   // [50,32,32]
    const float* __restrict__ w_comp,   // [200,50]
    const float* __restrict__ Aw,       // [32,128]
    const float* __restrict__ slw,      // [32,32]
    const int*  __restrict__ rel,       // [E]
    unsigned short* __restrict__ relwT_bf,
    unsigned short* __restrict__ aw_bf,
    unsigned short* __restrict__ slwT_bf,
    int* __restrict__ blockCountsT,
    float* __restrict__ out)
{
    int b = blockIdx.x, tid = threadIdx.x;
    if (b < N_REL) {
        __shared__ float wc[N_BASES];
        if (tid < N_BASES) wc[tid] = w_comp[b * N_BASES + tid];
        __syncthreads();
        // float4-coalesced weight loads (R4: scalar version was latency-bound)
        const float* wp = weight + tid * 4;
        float4 acc = make_float4(0.f, 0.f, 0.f, 0.f);
        #pragma unroll 10
        for (int bb = 0; bb < N_BASES; bb++) {
            float4 w = *(const float4*)(wp + bb * 1024);
            float c = wc[bb];
            acc.x = fmaf(c, w.x, acc.x); acc.y = fmaf(c, w.y, acc.y);
            acc.z = fmaf(c, w.z, acc.z); acc.w = fmaf(c, w.w, acc.w);
        }
        // flat f = tid*4 + j over [i][o] (o fastest): i = tid>>3, o = (tid*4&31)+j
        // write transposed: relwT[r][o][i]
        int i  = tid >> 3;
        int o0 = (tid * 4) & 31;
        unsigned short* dst = relwT_bf + b * 1024 + i;
        dst[(o0 + 0) * 32] = f2bf(acc.x);
        dst[(o0 + 1) * 32] = f2bf(acc.y);
        dst[(o0 + 2) * 32] = f2bf(acc.z);
        dst[(o0 + 3) * 32] = f2bf(acc.w);
    } else if (b < N_REL + ZERO_BLOCKS) {
        int base = (b - N_REL) * 1024 + tid * 4;
        if (base + 3 < OUT_ELEMS)
            *(float4*)(out + base) = make_float4(0.f, 0.f, 0.f, 0.f);
        else
            for (int k = 0; k < 4; k++)
                if (base + k < OUT_ELEMS) out[base + k] = 0.f;
    } else if (b == N_REL + ZERO_BLOCKS) {
        for (int x = tid; x < 32 * 128; x += 256) aw_bf[x] = f2bf(Aw[x]);
        for (int x = tid; x < 32 * 32; x += 256) {
            int i = x >> 5, j = x & 31;          // slw[i][j]
            slwT_bf[j * 32 + i] = f2bf(slw[x]);
        }
    } else {
        // per-block histogram: LDS atomics only; transposed stores so the
        // scan's per-bin reduction reads are contiguous int4s.
        __shared__ int h[N_REL];
        int blk = b - (N_REL + ZERO_BLOCKS + 1);
        for (int x = tid; x < N_REL; x += 256) h[x] = 0;
        __syncthreads();
        int e0 = blk * CHUNK;
        for (int e = e0 + tid; e < e0 + CHUNK; e += 256) {
            int r = rel[e]; r = r < 0 ? 0 : (r >= N_REL ? N_REL - 1 : r);
            atomicAdd(&h[r], 1);
        }
        __syncthreads();
        for (int x = tid; x < N_REL; x += 256)
            blockCountsT[x * NB_BLK + blk] = h[x];
    }
}

// Scan: one block. Thread r (<200) owns bin r: int4-reduce counts over blocks,
// Hillis-Steele LDS scan of 16-padded totals (replaces R2's serial thread-0
// loop), then int4 prefix writes of per-block bases. Persists offs/tots for
// scatter's dummy-writer blocks. offs[200] = padded grand total.
__global__ __launch_bounds__(256) void scan_kernel(
    const int* __restrict__ blockCountsT,
    int* __restrict__ blockBaseT,
    int* __restrict__ offs, int* __restrict__ tots)
{
    __shared__ int s0[256];
    __shared__ int pval[256];
    int tid = threadIdx.x;
    int tot = 0;
    if (tid < N_REL) {
        const int4* cp = (const int4*)(blockCountsT + tid * NB_BLK);
        #pragma unroll 5
        for (int b = 0; b < NB_BLK / 4; b++) {
            int4 c = cp[b];
            tot += c.x + c.y + c.z + c.w;
        }
    }
    int p = (tid < N_REL) ? ((tot + 15) & ~15) : 0;
    pval[tid] = p;
    s0[tid] = p;
    __syncthreads();
    #pragma unroll
    for (int d = 1; d < 256; d <<= 1) {
        int v = s0[tid];
        if (tid >= d) v += s0[tid - d];
        __syncthreads();
        s0[tid] = v;
        __syncthreads();
    }
    int off = s0[tid] - pval[tid];     // exclusive scan of padded totals
    if (tid < N_REL) { offs[tid] = off; tots[tid] = tot; }
    if (tid == 255) offs[N_REL] = s0[255];   // padded grand total
    if (tid < N_REL) {
        const int4* cp = (const int4*)(blockCountsT + tid * NB_BLK);
        int4* bp = (int4*)(blockBaseT + tid * NB_BLK);
        int run = off;
        #pragma unroll 5
        for (int b = 0; b < NB_BLK / 4; b++) {
            int4 c = cp[b];
            int4 w;
            w.x = run;
            w.y = w.x + c.x;
            w.z = w.y + c.y;
            w.w = w.z + c.z;
            run = w.w + c.w;
            bp[b] = w;
        }
    }
}

// Scatter: blocks [0,NB_BLK) claim positions from LDS cursors seeded with
// blockBaseT[*][blk]; one packed int4 store per edge. No global atomics.
// Blocks [NB_BLK, NB_BLK+8) write the <=3008 dummy slots (per-rel pad tails
// + the global tail up to PE_MAX). Within-rel order is nondeterministic
// (LDS atomic) — fp rounding only.
__global__ __launch_bounds__(256) void scatter_kernel(
    const int* __restrict__ edge0, const int* __restrict__ edge1,
    const int* __restrict__ rel,
    const int* __restrict__ blockBaseT,
    const int* __restrict__ offs, const int* __restrict__ tots,
    int4* __restrict__ slot4)
{
    int blk = blockIdx.x, tid = threadIdx.x;
    if (blk < NB_BLK) {
        __shared__ int cur[N_REL];
        for (int x = tid; x < N_REL; x += 256)
            cur[x] = blockBaseT[x * NB_BLK + blk];
        __syncthreads();
        int e0 = blk * CHUNK;
        #pragma unroll
        for (int e = e0 + tid; e < e0 + CHUNK; e += 256) {
            int r = rel[e];   r = r < 0 ? 0 : (r >= N_REL   ? N_REL   - 1 : r);
            int s = edge0[e]; s = s < 0 ? 0 : (s >= N_NODES ? N_NODES - 1 : s);
            int t = edge1[e]; t = t < 0 ? 0 : (t >= N_NODES ? N_NODES - 1 : t);
            int pos = atomicAdd(&cur[r], 1);
            slot4[pos] = make_int4(s, t, e, r);
        }
    } else {
        int db = blk - NB_BLK;               // 0..7
        const int4 dummy = make_int4(0, -1, 0, 0);
        // per-rel pad tails: [offs[r]+tots[r], offs[r]+pad16(tots[r]))
        for (int r = db; r < N_REL; r += N_DUMMY_BLOCKS) {
            int start = offs[r] + tots[r];
            int end   = offs[r] + ((tots[r] + 15) & ~15);
            for (int j = start + tid; j < end; j += 256)
                slot4[j] = dummy;
        }
        // global tail: [padTotal, PE_MAX)
        int padTotal = offs[N_REL];
        for (int j = padTotal + db * 256 + tid; j < PE_MAX; j += N_DUMMY_BLOCKS * 256)
            slot4[j] = dummy;
    }
}

// Edge kernel: one wave = 16 edges of ONE relation (guaranteed by padding),
// so ALL THREE products (h, cur, msg) are MFMAs. No LDS, no per-edge rel_w
// row streaming, no bpermute loop. Dummy slots (tgt == -1) masked at the atomic.
__global__ __launch_bounds__(256) void edge_kernel(
    const float* __restrict__ node_feat,  // [N,32]
    const float* __restrict__ ttr,        // [E,32]
    const float* __restrict__ tre,        // [E,32]
    const float* __restrict__ Ab,         // [32]
    const float* __restrict__ Bw,         // [1,32]
    const float* __restrict__ Bb,         // [1]
    const int4* __restrict__ slot4,       // [PE_MAX] {s, t(-1=dummy), e, r}
    const unsigned short* __restrict__ relwT_bf, // [200][32][32] bf16 (T)
    const unsigned short* __restrict__ aw_bf,    // [32][128] bf16
    const unsigned short* __restrict__ slwT_bf,  // [32][32]  bf16 (T)
    float* __restrict__ out)              // [N,32] fp32 (pre-zeroed)
{
    int tid  = threadIdx.x;
    int wave = tid >> 6;
    int lane = tid & 63;
    int m = lane & 15;          // edge row (A-frag) / out col n (B,C/D frag)
    int q = lane >> 4;          // quad: k-range / row-group
    int base = blockIdx.x * 64 + wave * 16;   // 3172*64 == PE_MAX exactly

    // lanes<16 load slot data (one coalesced 256B int4 burst); shfl the rest
    int s_ld = 0, t_ld = -1, e_ld = 0, r_ld = 0;
    if (lane < 16) {
        int4 v = slot4[base + lane];
        s_ld = v.x; t_ld = v.y; e_ld = v.z; r_ld = v.w;
    }
    // wave-uniform relation: slot 0 of each 16-group is real whenever the
    // group exists (padding sits at each rel's tail); fully-dummy tail groups
    // carry r=0, harmless since their atomics are masked.
    int r_w = __shfl(r_ld, 0, 64);

    int s_m = __shfl(s_ld, m, 64);
    int t_m = __shfl(t_ld, m, 64);
    int e_m = __shfl(e_ld, m, 64);
    int t_mc = t_m < 0 ? 0 : t_m;

    // ---- gather A-operand data (lane holds edge m, k = 8q..8q+7) ----
    const float* sp = node_feat + s_m * DIM + q * 8;
    float4 sv0 = *(const float4*)sp, sv1 = *(const float4*)(sp + 4);
    const float* tp = node_feat + t_mc * DIM + q * 8;
    float4 tv0 = *(const float4*)tp, tv1 = *(const float4*)(tp + 4);
    const float* rp = tre + e_m * DIM + q * 8;
    float4 rv0 = *(const float4*)rp, rv1 = *(const float4*)(rp + 4);
    const float* qp = ttr + e_m * DIM + q * 8;
    float4 qv0 = *(const float4*)qp, qv1 = *(const float4*)(qp + 4);

    short8 fsrc = cvt8(sv0, sv1);
    short8 ftgt = cvt8(tv0, tv1);
    short8 fre  = cvt8(rv0, rv1);
    short8 ftr  = cvt8(qv0, qv1);

    // ---- B-operand fragments (lane: n = m, k = 8q..8q+7) ----
    short8 bA[4][2], bS[2], bM[2];
    #pragma unroll
    for (int hh = 0; hh < 2; hh++) {
        #pragma unroll
        for (int c = 0; c < 4; c++)
            bA[c][hh] = *(const short8*)(aw_bf + (16 * hh + m) * 128 + 32 * c + 8 * q);
        bS[hh] = *(const short8*)(slwT_bf + (16 * hh + m) * 32 + 8 * q);
        bM[hh] = *(const short8*)(relwT_bf + r_w * 1024 + (16 * hh + m) * 32 + 8 * q);
    }

    // ---- MFMAs: h = Ecat@Aw^T + Ab ; cur = tgt@slw ; msg = src@rel_w[r] ----
    float ab0 = Ab[m], ab1 = Ab[16 + m];
    f32x4 hacc0 = {ab0, ab0, ab0, ab0};
    f32x4 hacc1 = {ab1, ab1, ab1, ab1};
    f32x4 cacc0 = {0.f, 0.f, 0.f, 0.f};
    f32x4 cacc1 = {0.f, 0.f, 0.f, 0.f};
    f32x4 macc0 = {0.f, 0.f, 0.f, 0.f};
    f32x4 macc1 = {0.f, 0.f, 0.f, 0.f};

    hacc0 = MFMA(fsrc, bA[0][0], hacc0);  hacc1 = MFMA(fsrc, bA[0][1], hacc1);
    hacc0 = MFMA(ftgt, bA[1][0], hacc0);  hacc1 = MFMA(ftgt, bA[1][1], hacc1);
    hacc0 = MFMA(fre,  bA[2][0], hacc0);  hacc1 = MFMA(fre,  bA[2][1], hacc1);
    hacc0 = MFMA(ftr,  bA[3][0], hacc0);  hacc1 = MFMA(ftr,  bA[3][1], hacc1);
    cacc0 = MFMA(ftgt, bS[0], cacc0);     cacc1 = MFMA(ftgt, bS[1], cacc1);
    macc0 = MFMA(fsrc, bM[0], macc0);     macc1 = MFMA(fsrc, bM[1], macc1);

    // ---- epilogue: gate a = sigmoid(relu(h)@Bw + Bb), combine, scatter ----
    float bw0 = Bw[m], bw1 = Bw[16 + m], Bb0 = Bb[0];
    float av[4];
    #pragma unroll
    for (int v = 0; v < 4; v++) {
        float p = fmaxf(hacc0[v], 0.f) * bw0 + fmaxf(hacc1[v], 0.f) * bw1;
        p += __shfl_xor(p, 1, 16);
        p += __shfl_xor(p, 2, 16);
        p += __shfl_xor(p, 4, 16);
        p += __shfl_xor(p, 8, 16);
        av[v] = 1.f / (1.f + __expf(-(p + Bb0)));
    }
    #pragma unroll
    for (int v = 0; v < 4; v++) {
        int row = 4 * q + v;
        int tv = __shfl(t_ld, row, 64);
        if (tv >= 0) {
            atomicAdd(&out[tv * DIM + m],      cacc0[v] + macc0[v] * av[v]);
            atomicAdd(&out[tv * DIM + 16 + m], cacc1[v] + macc1[v] * av[v]);
        }
    }
}

extern "C" void kernel_launch(void* const* d_in, const int* in_sizes, int n_in,
                              void* d_out, int out_size, void* d_ws, size_t ws_size,
                              hipStream_t stream) {
    const float* node_feat = (const float*)d_in[0];
    const float* ttr       = (const float*)d_in[1];
    const float* tre       = (const float*)d_in[2];
    const float* weight    = (const float*)d_in[3];
    const float* w_comp    = (const float*)d_in[4];
    const float* slw       = (const float*)d_in[5];
    const float* Aw        = (const float*)d_in[6];
    const float* Ab        = (const float*)d_in[7];
    const float* Bw        = (const float*)d_in[8];
    const float* Bb        = (const float*)d_in[9];
    const int*  total_edge = (const int*)d_in[10];
    const int*  rel        = (const int*)d_in[11];
    const int*  edge0 = total_edge;
    const int*  edge1 = total_edge + N_EDGES;

    char* ws = (char*)d_ws;
    unsigned short* relwT_bf = (unsigned short*)ws;
    unsigned short* aw_bf    = (unsigned short*)(ws + AWBF_OFF);
    unsigned short* slwT_bf  = (unsigned short*)(ws + SLWT_OFF);
    int*  blockCountsT = (int*)(ws + BCT_OFF);
    int*  blockBaseT   = (int*)(ws + BBT_OFF);
    int*  offs         = (int*)(ws + OFFS_OFF);
    int*  tots         = (int*)(ws + TOTS_OFF);
    int4* slot4        = (int4*)(ws + SLOT_OFF);
    float* out = (float*)d_out;

    prep_kernel<<<N_REL + ZERO_BLOCKS + 1 + NB_BLK, 256, 0, stream>>>(
        weight, w_comp, Aw, slw, rel, relwT_bf, aw_bf, slwT_bf,
        blockCountsT, out);

    scan_kernel<<<1, 256, 0, stream>>>(blockCountsT, blockBaseT, offs, tots);

    scatter_kernel<<<NB_BLK + N_DUMMY_BLOCKS, 256, 0, stream>>>(
        edge0, edge1, rel, blockBaseT, offs, tots, slot4);

    edge_kernel<<<PE_MAX / 64, 256, 0, stream>>>(
        node_feat, ttr, tre, Ab, Bw, Bb,
        slot4, relwT_bf, aw_bf, slwT_bf, out);
}